// Round 1
// baseline (460.366 us; speedup 1.0000x reference)
//
#include <hip/hip_runtime.h>

#define N_TOK 49152

// bf16 fragment blob segment offsets (elements), per expert
#define PER_E  155648
#define W1F_OFF 0
#define W2F_OFF 32768
#define W3F_OFF 98304
#define S1F_OFF 131072
#define S2F_OFF 147456

// d_out float offsets
#define TRAJ_OFF 0
#define SCORE_OFF 5898240
#define AUX_OFF  5947392
#define PROB_OFF 5947393

typedef __attribute__((ext_vector_type(8))) short short8v;
typedef __attribute__((ext_vector_type(4))) float f32x4;

__device__ __forceinline__ unsigned short f2bf(float f) {
  unsigned int u = __float_as_uint(f);
  u = (u + 0x7FFFu + ((u >> 16) & 1u)) >> 16;
  return (unsigned short)u;
}
__device__ __forceinline__ float geluf(float v) {
  return 0.5f * v * (1.0f + erff(v * 0.70710678118654752f));
}

// ---------------- weight prep: fp32 -> bf16, MFMA fragment-major ----------------
__global__ __launch_bounds__(256) void prep_weights(
    const float* __restrict__ tW1, const float* __restrict__ tW2, const float* __restrict__ tW3,
    const float* __restrict__ sW1, const float* __restrict__ sW2,
    unsigned short* __restrict__ blob)
{
  int id = blockIdx.x * 256 + threadIdx.x;
  if (id >= 6 * PER_E) return;
  int e = id / PER_E;
  int r = id - e * PER_E;
  const float* src; int NF, ncols, segbase;
  if (r < W2F_OFF)      { segbase = W1F_OFF; NF = 16; ncols = 256; src = tW1 + e * 128 * 256; }
  else if (r < W3F_OFF) { segbase = W2F_OFF; NF = 16; ncols = 256; src = tW2 + e * 256 * 256; }
  else if (r < S1F_OFF) { segbase = W3F_OFF; NF = 8;  ncols = 120; src = tW3 + e * 256 * 120; }
  else if (r < S2F_OFF) { segbase = S1F_OFF; NF = 8;  ncols = 128; src = sW1 + e * 128 * 128; }
  else                  { segbase = S2F_OFF; NF = 4;  ncols = 64;  src = sW2 + e * 128 * 64;  }
  int q = r - segbase;
  int j = q & 7;
  int lane = (q >> 3) & 63;
  int f = q >> 9;
  int fc = f % NF;
  int kk = f / NF;
  int k = kk * 32 + ((lane >> 4) << 3) + j;
  int col = fc * 16 + (lane & 15);
  float v = (col < ncols) ? src[k * ncols + col] : 0.0f;
  blob[id] = f2bf(v);
}

// ---------------- fused fp32 router: probs, top2, buckets, prob sums ----------------
__global__ __launch_bounds__(256) void router_kernel(
    const float* __restrict__ x,
    const float* __restrict__ rW1, const float* __restrict__ rb1,
    const float* __restrict__ rW2, const float* __restrict__ rb2,
    const float* __restrict__ rW3, const float* __restrict__ rb3,
    float* __restrict__ probs_out,
    int* __restrict__ pairTok, float* __restrict__ pairW,
    int* __restrict__ cnt, float* __restrict__ probsum)
{
  __shared__ float xs[32][128];
  __shared__ float h1[32][256];
  __shared__ float h2[32][132];   // padded (layer-3 scalar reads)
  __shared__ float lg[32][8];
  __shared__ float psum[8];
  __shared__ int lcnt[8], gbase[8];

  int tid = threadIdx.x;
  int tok0 = blockIdx.x * 32;

  for (int i = tid; i < 32 * 32; i += 256) {   // 32 rows x 32 float4
    int row = i >> 5, c4 = i & 31;
    *(f32x4*)&xs[row][c4 * 4] = *(const f32x4*)(x + (size_t)(tok0 + row) * 128 + c4 * 4);
  }
  if (tid < 8) { psum[tid] = 0.f; lcnt[tid] = 0; }
  __syncthreads();

  // layer1: D=128 -> 256.  thread: units u0..u0+3, tokens t0..t0+7
  {
    int u0 = (tid & 63) * 4;
    int t0 = (tid >> 6) * 8;
    float a[8][4];
    #pragma unroll
    for (int t = 0; t < 8; ++t)
      #pragma unroll
      for (int u = 0; u < 4; ++u) a[t][u] = 0.f;
    for (int db = 0; db < 32; ++db) {
      int d = db * 4;
      f32x4 wv[4];
      #pragma unroll
      for (int dd = 0; dd < 4; ++dd) wv[dd] = *(const f32x4*)(rW1 + (size_t)(d + dd) * 256 + u0);
      #pragma unroll
      for (int tt = 0; tt < 8; ++tt) {
        f32x4 xv = *(const f32x4*)&xs[t0 + tt][d];
        #pragma unroll
        for (int dd = 0; dd < 4; ++dd)
          #pragma unroll
          for (int uu = 0; uu < 4; ++uu) a[tt][uu] += xv[dd] * wv[dd][uu];
      }
    }
    f32x4 bv = *(const f32x4*)(rb1 + u0);
    #pragma unroll
    for (int tt = 0; tt < 8; ++tt) {
      f32x4 o;
      #pragma unroll
      for (int uu = 0; uu < 4; ++uu) o[uu] = geluf(a[tt][uu] + bv[uu]);
      *(f32x4*)&h1[t0 + tt][u0] = o;
    }
  }
  __syncthreads();

  // layer2: 256 -> 128. thread: units u0..u0+3, tokens t0..t0+3
  {
    int u0 = (tid & 31) * 4;
    int t0 = (tid >> 5) * 4;
    float a[4][4];
    #pragma unroll
    for (int t = 0; t < 4; ++t)
      #pragma unroll
      for (int u = 0; u < 4; ++u) a[t][u] = 0.f;
    for (int db = 0; db < 64; ++db) {
      int d = db * 4;
      f32x4 wv[4];
      #pragma unroll
      for (int dd = 0; dd < 4; ++dd) wv[dd] = *(const f32x4*)(rW2 + (size_t)(d + dd) * 128 + u0);
      #pragma unroll
      for (int tt = 0; tt < 4; ++tt) {
        f32x4 xv = *(const f32x4*)&h1[t0 + tt][d];
        #pragma unroll
        for (int dd = 0; dd < 4; ++dd)
          #pragma unroll
          for (int uu = 0; uu < 4; ++uu) a[tt][uu] += xv[dd] * wv[dd][uu];
      }
    }
    f32x4 bv = *(const f32x4*)(rb2 + u0);
    #pragma unroll
    for (int tt = 0; tt < 4; ++tt) {
      f32x4 o;
      #pragma unroll
      for (int uu = 0; uu < 4; ++uu) o[uu] = geluf(a[tt][uu] + bv[uu]);
      *(f32x4*)&h2[t0 + tt][u0] = o;
    }
  }
  __syncthreads();

  // layer3: 128 -> 6 logits
  if (tid < 192) {
    int t = tid / 6, e = tid - t * 6;
    float s = rb3[e];
    for (int d = 0; d < 128; ++d) s += h2[t][d] * rW3[d * 6 + e];
    lg[t][e] = s;
  }
  __syncthreads();

  int i1 = 0, i2 = 0, lp1 = 0, lp2 = 0;
  float w1 = 0.f, w2 = 0.f;
  int myTok = tok0 + tid;
  if (tid < 32) {
    float l0[6];
    #pragma unroll
    for (int e = 0; e < 6; ++e) l0[e] = lg[tid][e];
    float m = l0[0];
    #pragma unroll
    for (int e = 1; e < 6; ++e) m = fmaxf(m, l0[e]);
    float pe[6]; float ssum = 0.f;
    #pragma unroll
    for (int e = 0; e < 6; ++e) { pe[e] = expf(l0[e] - m); ssum += pe[e]; }
    float inv = 1.f / ssum;
    #pragma unroll
    for (int e = 0; e < 6; ++e) {
      float pr = pe[e] * inv;
      probs_out[(size_t)myTok * 6 + e] = pr;
      atomicAdd(&psum[e], pr);
    }
    // top-2, ties -> lower index (matches jax.lax.top_k)
    float v1 = l0[0]; i1 = 0; float v2 = -1e30f; i2 = -1;
    #pragma unroll
    for (int e = 1; e < 6; ++e) {
      float v = l0[e];
      if (v > v1) { v2 = v1; i2 = i1; v1 = v; i1 = e; }
      else if (v > v2) { v2 = v; i2 = e; }
    }
    float e2 = expf(v2 - v1);
    float denom = 1.f / (1.f + e2);
    w1 = denom; w2 = e2 * denom;
    lp1 = atomicAdd(&lcnt[i1], 1);
    lp2 = atomicAdd(&lcnt[i2], 1);
  }
  __syncthreads();
  if (tid < 6) gbase[tid] = atomicAdd(&cnt[tid], lcnt[tid]);
  __syncthreads();
  if (tid < 32) {
    int g1 = gbase[i1] + lp1, g2 = gbase[i2] + lp2;
    pairTok[i1 * N_TOK + g1] = myTok; pairW[i1 * N_TOK + g1] = w1;
    pairTok[i2 * N_TOK + g2] = myTok; pairW[i2 * N_TOK + g2] = w2;
  }
  if (tid < 6) atomicAdd(&probsum[tid], psum[tid]);
}

// ---------------- aux loss ----------------
__global__ void aux_kernel(const float* __restrict__ probsum, float* __restrict__ auxout)
{
  if (threadIdx.x == 0 && blockIdx.x == 0) {
    float ent = 0.f, l2 = 0.f;
    for (int e = 0; e < 6; ++e) {
      float avg = probsum[e] / (float)N_TOK;
      ent -= avg * logf(avg + 1e-8f);
      float d = avg - (1.0f / 6.0f);
      l2 += d * d;
    }
    l2 *= (1.0f / 6.0f);
    auxout[0] = -ent * 0.01f + 0.01f * l2;
  }
}

// ---------------- expert tile GEMM helpers ----------------
template<int KSTEPS, int NF>
__device__ __forceinline__ void mm_tile(const unsigned short* As, int rowStride,
                                        const unsigned short* __restrict__ Bf,
                                        int lane, int wrow0, f32x4* acc)
{
  #pragma unroll
  for (int fc = 0; fc < NF; ++fc) acc[fc] = (f32x4){0.f, 0.f, 0.f, 0.f};
  int row = wrow0 + (lane & 15);
  int hi = lane >> 4;
  #pragma unroll
  for (int kk = 0; kk < KSTEPS; ++kk) {
    int byteoff = (row * rowStride + (kk * 32 + hi * 8) * 2) ^ ((row & 7) << 4);
    short8v a = *(const short8v*)((const char*)As + byteoff);
    #pragma unroll
    for (int fc = 0; fc < NF; ++fc) {
      short8v b = *(const short8v*)(Bf + ((size_t)(kk * NF + fc) * 64 + lane) * 8);
      acc[fc] = __builtin_amdgcn_mfma_f32_16x16x32_bf16(a, b, acc[fc], 0, 0, 0);
    }
  }
}

template<int NF>
__device__ __forceinline__ void epi_gelu_lds(const f32x4* acc, const float* __restrict__ bias,
                                             unsigned short* Ds, int rowStride, int lane, int wrow0)
{
  int colb = lane & 15;
  int rbase = wrow0 + ((lane >> 4) << 2);
  #pragma unroll
  for (int fc = 0; fc < NF; ++fc) {
    int col = fc * 16 + colb;
    float bv = bias[col];
    #pragma unroll
    for (int r = 0; r < 4; ++r) {
      int row = rbase + r;
      unsigned short h = f2bf(geluf(acc[fc][r] + bv));
      int byteoff = (row * rowStride + col * 2) ^ ((row & 7) << 4);
      *(unsigned short*)((char*)Ds + byteoff) = h;
    }
  }
}

// ---------------- grouped sparse expert kernel (bf16 MFMA) ----------------
__global__ __launch_bounds__(256, 2) void expert_kernel(
    const float* __restrict__ x,
    const unsigned short* __restrict__ blob,
    const float* __restrict__ tb1, const float* __restrict__ tb2, const float* __restrict__ tb3,
    const float* __restrict__ sb1, const float* __restrict__ sb2,
    const float* __restrict__ sW3, const float* __restrict__ sb3,
    const int* __restrict__ pairTok, const float* __restrict__ pairW,
    const int* __restrict__ cnt,
    float* __restrict__ traj_out, float* __restrict__ score_out)
{
  int e = blockIdx.y;
  int tile = blockIdx.x;
  int count = cnt[e];
  int base = tile * 64;
  if (base >= count) return;

  __shared__ unsigned short Xs[64 * 128];   // X tile, bf16, swizzled
  __shared__ unsigned short B1[64 * 256];   // H1
  __shared__ unsigned short B2[64 * 256];   // SH1 (stride 256) then H2 (stride 512)

  int tid = threadIdx.x;
  int lane = tid & 63;
  int w = tid >> 6;
  int wrow0 = w * 16;
  const int pbase = e * N_TOK + base;
  const unsigned short* eblob = blob + (size_t)e * PER_E;

  // stage gathered X -> bf16 LDS
  for (int ch = tid; ch < 64 * 16; ch += 256) {
    int row = ch >> 4, cb = ch & 15;
    int tok = (base + row < count) ? pairTok[pbase + row] : 0;
    const f32x4* xp = (const f32x4*)(x + (size_t)tok * 128 + cb * 8);
    f32x4 lo = xp[0], hi = xp[1];
    short8v v;
    v[0] = (short)f2bf(lo[0]); v[1] = (short)f2bf(lo[1]); v[2] = (short)f2bf(lo[2]); v[3] = (short)f2bf(lo[3]);
    v[4] = (short)f2bf(hi[0]); v[5] = (short)f2bf(hi[1]); v[6] = (short)f2bf(hi[2]); v[7] = (short)f2bf(hi[3]);
    int byteoff = (row * 256 + cb * 16) ^ ((row & 7) << 4);
    *(short8v*)((char*)Xs + byteoff) = v;
  }
  __syncthreads();

  f32x4 acc[16];

  // T1: X[64x128] @ W1[128x256] -> H1
  mm_tile<4, 16>(Xs, 256, eblob + W1F_OFF, lane, wrow0, acc);
  epi_gelu_lds<16>(acc, tb1 + e * 256, B1, 512, lane, wrow0);
  __syncthreads();

  // S1: X @ sW1[128x128] -> SH1 (in B2, stride 256)
  mm_tile<4, 8>(Xs, 256, eblob + S1F_OFF, lane, wrow0, acc);
  epi_gelu_lds<8>(acc, sb1 + e * 128, B2, 256, lane, wrow0);
  __syncthreads();

  // S2: SH1 @ sW2[128x64] -> gelu -> dot sW3 -> score
  mm_tile<4, 4>(B2, 256, eblob + S2F_OFF, lane, wrow0, acc);
  {
    int colb = lane & 15;
    float p[4] = {0.f, 0.f, 0.f, 0.f};
    #pragma unroll
    for (int fc = 0; fc < 4; ++fc) {
      int col = fc * 16 + colb;
      float bv = sb2[e * 64 + col];
      float wv = sW3[e * 64 + col];
      #pragma unroll
      for (int r = 0; r < 4; ++r) p[r] += geluf(acc[fc][r] + bv) * wv;
    }
    #pragma unroll
    for (int r = 0; r < 4; ++r) {
      p[r] += __shfl_xor(p[r], 1);
      p[r] += __shfl_xor(p[r], 2);
      p[r] += __shfl_xor(p[r], 4);
      p[r] += __shfl_xor(p[r], 8);
    }
    if ((lane & 15) == 0) {
      #pragma unroll
      for (int r = 0; r < 4; ++r) {
        int row = wrow0 + ((lane >> 4) << 2) + r;
        if (base + row < count) {
          int tok = pairTok[pbase + row];
          float gw = pairW[pbase + row];
          atomicAdd(&score_out[tok], gw * (p[r] + sb3[e]));
        }
      }
    }
  }
  __syncthreads();

  // T2: H1 @ W2[256x256] -> H2 (in B2, stride 512)
  mm_tile<8, 16>(B1, 512, eblob + W2F_OFF, lane, wrow0, acc);
  epi_gelu_lds<16>(acc, tb2 + e * 256, B2, 512, lane, wrow0);
  __syncthreads();

  // T3: H2 @ W3[256x120(pad128)] -> weighted atomic out
  mm_tile<8, 8>(B2, 512, eblob + W3F_OFF, lane, wrow0, acc);
  {
    int colb = lane & 15;
    int rbase = wrow0 + ((lane >> 4) << 2);
    int toks[4]; float gws[4]; bool val[4];
    #pragma unroll
    for (int r = 0; r < 4; ++r) {
      int row = rbase + r;
      val[r] = (base + row < count);
      toks[r] = val[r] ? pairTok[pbase + row] : 0;
      gws[r]  = val[r] ? pairW[pbase + row] : 0.f;
    }
    #pragma unroll
    for (int fc = 0; fc < 8; ++fc) {
      int col = fc * 16 + colb;
      if (col < 120) {
        float bv = tb3[e * 120 + col];
        #pragma unroll
        for (int r = 0; r < 4; ++r) {
          if (val[r]) atomicAdd(&traj_out[(size_t)toks[r] * 120 + col], gws[r] * (acc[fc][r] + bv));
        }
      }
    }
  }
}

extern "C" void kernel_launch(void* const* d_in, const int* in_sizes, int n_in,
                              void* d_out, int out_size, void* d_ws, size_t ws_size,
                              hipStream_t stream) {
  (void)in_sizes; (void)n_in; (void)out_size; (void)ws_size;
  const float* x   = (const float*)d_in[0];
  const float* rW1 = (const float*)d_in[1];
  const float* rb1 = (const float*)d_in[2];
  const float* rW2 = (const float*)d_in[3];
  const float* rb2 = (const float*)d_in[4];
  const float* rW3 = (const float*)d_in[5];
  const float* rb3 = (const float*)d_in[6];
  const float* tW1 = (const float*)d_in[7];
  const float* tb1 = (const float*)d_in[8];
  const float* tW2 = (const float*)d_in[9];
  const float* tb2 = (const float*)d_in[10];
  const float* tW3 = (const float*)d_in[11];
  const float* tb3 = (const float*)d_in[12];
  const float* sW1 = (const float*)d_in[13];
  const float* sb1 = (const float*)d_in[14];
  const float* sW2 = (const float*)d_in[15];
  const float* sb2 = (const float*)d_in[16];
  const float* sW3 = (const float*)d_in[17];
  const float* sb3 = (const float*)d_in[18];
  float* out = (float*)d_out;

  // workspace carve
  char* wsb = (char*)d_ws;
  int*   cnt     = (int*)wsb;                                   // 8 ints
  float* probsum = (float*)(wsb + 32);                          // 8 floats
  int*   pairTok = (int*)(wsb + 64);                            // 6*N
  float* pairW   = (float*)(wsb + 64 + (size_t)6 * N_TOK * 4);  // 6*N
  unsigned short* blob = (unsigned short*)(wsb + 64 + (size_t)6 * N_TOK * 8);

  hipMemsetAsync(wsb, 0, 64, stream);
  hipMemsetAsync(d_out, 0, (size_t)(N_TOK * 121) * 4, stream);  // traj + scores

  prep_weights<<<(6 * PER_E) / 256, 256, 0, stream>>>(tW1, tW2, tW3, sW1, sW2, blob);
  router_kernel<<<N_TOK / 32, 256, 0, stream>>>(x, rW1, rb1, rW2, rb2, rW3, rb3,
                                                out + PROB_OFF, pairTok, pairW, cnt, probsum);
  aux_kernel<<<1, 64, 0, stream>>>(probsum, out + AUX_OFF);
  expert_kernel<<<dim3(768, 6), 256, 0, stream>>>(x, blob, tb1, tb2, tb3, sb1, sb2, sW3, sb3,
                                                  pairTok, pairW, cnt, out + TRAJ_OFF, out + SCORE_OFF);
}

// Round 2
// 414.178 us; speedup vs baseline: 1.1115x; 1.1115x over previous
//
#include <hip/hip_runtime.h>

#define N_TOK 49152
#define PER_E 155648      // 38 chunks * 4096 bf16 elems per expert
#define CHUNKS 38
#define TILE 128

// d_out float offsets
#define TRAJ_OFF 0
#define SCORE_OFF 5898240
#define AUX_OFF  5947392
#define PROB_OFF 5947393

// LDS element offsets (expert kernel)
#define H1_OFF  0        // 128 x 256, stride 512B
#define XS_OFF  32768    // 128 x 128, stride 256B
#define SH1_OFF 49152    // 128 x 128, stride 256B
#define H2_OFF  32768    // 128 x 256, stride 512B (overlays XS+SH1)
#define WB_OFF  65536    // 3 x 4096 ring

typedef __attribute__((ext_vector_type(8))) short short8v;
typedef __attribute__((ext_vector_type(4))) float f32x4;
typedef __attribute__((ext_vector_type(4))) unsigned short u16x4;

typedef __attribute__((address_space(3))) unsigned char lds_byte;
typedef __attribute__((address_space(1))) const unsigned char gl_byte;

__device__ __forceinline__ unsigned short f2bf(float f) {
  unsigned int u = __float_as_uint(f);
  u = (u + 0x7FFFu + ((u >> 16) & 1u)) >> 16;
  return (unsigned short)u;
}
__device__ __forceinline__ float bf2f(unsigned short h) {
  return __uint_as_float(((unsigned int)h) << 16);
}
__device__ __forceinline__ float geluf(float v) {
  return 0.5f * v * (1.0f + erff(v * 0.70710678118654752f));
}

// ---------------- weight prep: fp32 -> bf16, chunked fragment-major ----------------
// blob per expert = 38 chunks of 4096 elems; chunk = 8 frags of 512; frag elem = i*512 + lane*8 + j
// frag value = W[k][col], k = kk*32 + (lane>>4)*8 + j, col = fc*16 + (lane&15)
__global__ __launch_bounds__(256) void prep_weights(
    const float* __restrict__ tW1, const float* __restrict__ tW2, const float* __restrict__ tW3,
    const float* __restrict__ sW1, const float* __restrict__ sW2,
    unsigned short* __restrict__ blob)
{
  int id = blockIdx.x * 256 + threadIdx.x;
  if (id >= 6 * PER_E) return;
  int e = id / PER_E;
  int r = id - e * PER_E;
  int c = r >> 12;
  int q = r & 4095;
  int i = q >> 9;
  int lane = (q >> 3) & 63;
  int j = q & 7;
  const float* src; int ncols, kk, fc;
  if (c < 8)       { src = tW1 + e * 32768; ncols = 256; kk = c >> 1;              fc = ((c & 1) << 3) + i; }
  else if (c < 12) { src = sW1 + e * 16384; ncols = 128; kk = c - 8;               fc = i; }
  else if (c < 14) { src = sW2 + e * 8192;  ncols = 64;  kk = ((c - 12) << 1) + (i >> 2); fc = i & 3; }
  else if (c < 30) { int t = c - 14; src = tW2 + e * 65536; ncols = 256; kk = t >> 1; fc = ((t & 1) << 3) + i; }
  else             { src = tW3 + e * 30720; ncols = 120; kk = c - 30;              fc = i; }
  int k = (kk << 5) + ((lane >> 4) << 3) + j;
  int col = (fc << 4) + (lane & 15);
  blob[id] = f2bf(col < ncols ? src[k * ncols + col] : 0.0f);
}

// ---------------- fused fp32 router ----------------
__global__ __launch_bounds__(256) void router_kernel(
    const float* __restrict__ x,
    const float* __restrict__ rW1, const float* __restrict__ rb1,
    const float* __restrict__ rW2, const float* __restrict__ rb2,
    const float* __restrict__ rW3, const float* __restrict__ rb3,
    float* __restrict__ probs_out,
    int* __restrict__ pairTok, float* __restrict__ pairW, int* __restrict__ pairIdx,
    int* __restrict__ cnt, float* __restrict__ probsum)
{
  __shared__ float xs[32][128];
  __shared__ float h1[32][256];
  __shared__ float h2[32][132];
  __shared__ float lg[32][8];
  __shared__ float psum[8];
  __shared__ int lcnt[8], gbase[8];

  int tid = threadIdx.x;
  int tok0 = blockIdx.x * 32;

  for (int i = tid; i < 32 * 32; i += 256) {
    int row = i >> 5, c4 = i & 31;
    *(f32x4*)&xs[row][c4 * 4] = *(const f32x4*)(x + (size_t)(tok0 + row) * 128 + c4 * 4);
  }
  if (tid < 8) { psum[tid] = 0.f; lcnt[tid] = 0; }
  __syncthreads();

  {
    int u0 = (tid & 63) * 4;
    int t0 = (tid >> 6) * 8;
    float a[8][4];
    #pragma unroll
    for (int t = 0; t < 8; ++t)
      #pragma unroll
      for (int u = 0; u < 4; ++u) a[t][u] = 0.f;
    for (int db = 0; db < 32; ++db) {
      int d = db * 4;
      f32x4 wv[4];
      #pragma unroll
      for (int dd = 0; dd < 4; ++dd) wv[dd] = *(const f32x4*)(rW1 + (size_t)(d + dd) * 256 + u0);
      #pragma unroll
      for (int tt = 0; tt < 8; ++tt) {
        f32x4 xv = *(const f32x4*)&xs[t0 + tt][d];
        #pragma unroll
        for (int dd = 0; dd < 4; ++dd)
          #pragma unroll
          for (int uu = 0; uu < 4; ++uu) a[tt][uu] += xv[dd] * wv[dd][uu];
      }
    }
    f32x4 bv = *(const f32x4*)(rb1 + u0);
    #pragma unroll
    for (int tt = 0; tt < 8; ++tt) {
      f32x4 o;
      #pragma unroll
      for (int uu = 0; uu < 4; ++uu) o[uu] = geluf(a[tt][uu] + bv[uu]);
      *(f32x4*)&h1[t0 + tt][u0] = o;
    }
  }
  __syncthreads();

  {
    int u0 = (tid & 31) * 4;
    int t0 = (tid >> 5) * 4;
    float a[4][4];
    #pragma unroll
    for (int t = 0; t < 4; ++t)
      #pragma unroll
      for (int u = 0; u < 4; ++u) a[t][u] = 0.f;
    for (int db = 0; db < 64; ++db) {
      int d = db * 4;
      f32x4 wv[4];
      #pragma unroll
      for (int dd = 0; dd < 4; ++dd) wv[dd] = *(const f32x4*)(rW2 + (size_t)(d + dd) * 128 + u0);
      #pragma unroll
      for (int tt = 0; tt < 4; ++tt) {
        f32x4 xv = *(const f32x4*)&h1[t0 + tt][d];
        #pragma unroll
        for (int dd = 0; dd < 4; ++dd)
          #pragma unroll
          for (int uu = 0; uu < 4; ++uu) a[tt][uu] += xv[dd] * wv[dd][uu];
      }
    }
    f32x4 bv = *(const f32x4*)(rb2 + u0);
    #pragma unroll
    for (int tt = 0; tt < 4; ++tt) {
      f32x4 o;
      #pragma unroll
      for (int uu = 0; uu < 4; ++uu) o[uu] = geluf(a[tt][uu] + bv[uu]);
      *(f32x4*)&h2[t0 + tt][u0] = o;
    }
  }
  __syncthreads();

  if (tid < 192) {
    int t = tid / 6, e = tid - t * 6;
    float s = rb3[e];
    for (int d = 0; d < 128; ++d) s += h2[t][d] * rW3[d * 6 + e];
    lg[t][e] = s;
  }
  __syncthreads();

  int i1 = 0, i2 = 0, lp1 = 0, lp2 = 0;
  float w1 = 0.f, w2 = 0.f;
  int myTok = tok0 + tid;
  if (tid < 32) {
    float l0[6];
    #pragma unroll
    for (int e = 0; e < 6; ++e) l0[e] = lg[tid][e];
    float m = l0[0];
    #pragma unroll
    for (int e = 1; e < 6; ++e) m = fmaxf(m, l0[e]);
    float pe[6]; float ssum = 0.f;
    #pragma unroll
    for (int e = 0; e < 6; ++e) { pe[e] = expf(l0[e] - m); ssum += pe[e]; }
    float inv = 1.f / ssum;
    #pragma unroll
    for (int e = 0; e < 6; ++e) {
      float pr = pe[e] * inv;
      probs_out[(size_t)myTok * 6 + e] = pr;
      atomicAdd(&psum[e], pr);
    }
    float v1 = l0[0]; i1 = 0; float v2 = -1e30f; i2 = -1;
    #pragma unroll
    for (int e = 1; e < 6; ++e) {
      float v = l0[e];
      if (v > v1) { v2 = v1; i2 = i1; v1 = v; i1 = e; }
      else if (v > v2) { v2 = v; i2 = e; }
    }
    float e2 = expf(v2 - v1);
    float denom = 1.f / (1.f + e2);
    w1 = denom; w2 = e2 * denom;
    lp1 = atomicAdd(&lcnt[i1], 1);
    lp2 = atomicAdd(&lcnt[i2], 1);
  }
  __syncthreads();
  if (tid < 6) gbase[tid] = atomicAdd(&cnt[tid], lcnt[tid]);
  __syncthreads();
  if (tid < 32) {
    int g1 = gbase[i1] + lp1, g2 = gbase[i2] + lp2;
    pairTok[i1 * N_TOK + g1] = myTok; pairW[i1 * N_TOK + g1] = w1;
    pairTok[i2 * N_TOK + g2] = myTok; pairW[i2 * N_TOK + g2] = w2;
    pairIdx[2 * myTok]     = i1 * N_TOK + g1;
    pairIdx[2 * myTok + 1] = i2 * N_TOK + g2;
  }
  if (tid < 6) atomicAdd(&probsum[tid], psum[tid]);
}

// ---------------- aux loss + csum ----------------
__global__ void aux_kernel(const float* __restrict__ probsum, const int* __restrict__ cnt,
                           int* __restrict__ csum, float* __restrict__ auxout)
{
  if (threadIdx.x == 0 && blockIdx.x == 0) {
    int s = 0;
    for (int e = 0; e < 6; ++e) { csum[e] = s; s += cnt[e]; }
    float ent = 0.f, l2 = 0.f;
    for (int e = 0; e < 6; ++e) {
      float avg = probsum[e] / (float)N_TOK;
      ent -= avg * logf(avg + 1e-8f);
      float d = avg - (1.0f / 6.0f);
      l2 += d * d;
    }
    l2 *= (1.0f / 6.0f);
    auxout[0] = -ent * 0.01f + 0.01f * l2;
  }
}

// ---------------- expert kernel helpers ----------------
__device__ __forceinline__ void stage1k(const unsigned short* g, unsigned short* l) {
  __builtin_amdgcn_global_load_lds((gl_byte*)g, (lds_byte*)l, 16, 0, 0);
}

__device__ __forceinline__ short8v read_a(const unsigned short* lds, int offEl, int strideB, int row, int koff) {
  int b = (row * strideB + koff * 2) ^ ((row & 7) << 4);
  return *(const short8v*)((const char*)(lds + offEl) + b);
}

template<int NF>
__device__ __forceinline__ void epi_gelu(const f32x4* acc, const float* __restrict__ bias,
                                         unsigned short* dst, int strideB, int lane, int wrow0)
{
  int colb = lane & 15;
  int rbase = wrow0 + ((lane >> 4) << 2);
  #pragma unroll
  for (int fc = 0; fc < NF; ++fc) {
    int col = fc * 16 + colb;
    float bv = bias[col];
    #pragma unroll
    for (int r = 0; r < 4; ++r) {
      int row = rbase + r;
      unsigned short h = f2bf(geluf(acc[fc][r] + bv));
      int b = (row * strideB + col * 2) ^ ((row & 7) << 4);
      *(unsigned short*)((char*)dst + b) = h;
    }
  }
}

// one barrier + counted vmcnt per chunk; 3-slot LDS ring; stage c+2 AFTER barrier
#define PIPE(cc) do { \
    if ((cc) < CHUNKS - 1) asm volatile("s_waitcnt vmcnt(1)" ::: "memory"); \
    else                   asm volatile("s_waitcnt vmcnt(0)" ::: "memory"); \
    __builtin_amdgcn_s_barrier(); \
    __builtin_amdgcn_sched_barrier(0); \
    if ((cc) + 2 < CHUNKS) stage1k(eblob + ((cc) + 2) * 4096 + w * 512 + lane * 8, wb + (((cc) + 2) % 3) * 4096 + w * 512); \
  } while (0)

// ---------------- grouped sparse expert kernel, chunk-pipelined ----------------
template<int OUTMODE>   // 0 = scratch(pair partials), 1 = atomicAdd into d_out
__global__ __launch_bounds__(512, 1) void expert_kernel(
    const float* __restrict__ x,
    const unsigned short* __restrict__ blob,
    const float* __restrict__ tb1, const float* __restrict__ tb2, const float* __restrict__ tb3,
    const float* __restrict__ sb1, const float* __restrict__ sb2,
    const float* __restrict__ sW3, const float* __restrict__ sb3,
    const int* __restrict__ pairTok, const float* __restrict__ pairW,
    const int* __restrict__ cnt, const int* __restrict__ csum,
    float* __restrict__ traj_out, float* __restrict__ score_out,
    unsigned short* __restrict__ trajP, float* __restrict__ scoreP)
{
  int e = blockIdx.y;
  int base = blockIdx.x * TILE;
  int count = cnt[e];
  if (base >= count) return;

  __shared__ unsigned short lds[77824];   // 152KB: acts (64KB+overlay) + 3x8KB weight ring
  __shared__ int   toksLds[TILE];
  __shared__ float gwsLds[TILE];

  int tid = threadIdx.x;
  int lane = tid & 63;
  int w = tid >> 6;            // 8 waves
  int wrow0 = w * 16;
  int hi8 = (lane >> 4) << 3;
  int arow = wrow0 + (lane & 15);
  unsigned short* wb = lds + WB_OFF;
  const unsigned short* eblob = blob + (size_t)e * PER_E;
  int slotbase = csum[e] + base;

  if (tid < TILE) {
    int row = tid;
    int idx = e * N_TOK + base + ((base + row < count) ? row : 0);
    toksLds[row] = pairTok[idx];
    gwsLds[row] = (base + row < count) ? pairW[idx] : 0.f;
  }
  __syncthreads();

  // gather X (128 rows x 512B) -> regs, issue first two weight chunks, convert -> Xs
  f32x4 gx[8];
  #pragma unroll
  for (int it = 0; it < 8; ++it) {
    int task = it * 512 + tid;
    int row = task >> 5, cb = task & 31;
    int tok = toksLds[row];
    gx[it] = *(const f32x4*)(x + (size_t)tok * 128 + cb * 4);
  }
  stage1k(eblob + 0 * 4096 + w * 512 + lane * 8, wb + 0 * 4096 + w * 512);
  stage1k(eblob + 1 * 4096 + w * 512 + lane * 8, wb + 1 * 4096 + w * 512);
  #pragma unroll
  for (int it = 0; it < 8; ++it) {
    int task = it * 512 + tid;
    int row = task >> 5, cb = task & 31;
    u16x4 hv;
    #pragma unroll
    for (int jj = 0; jj < 4; ++jj) hv[jj] = f2bf(gx[it][jj]);
    int b = (row * 256 + cb * 8) ^ ((row & 7) << 4);
    *(u16x4*)((char*)(lds + XS_OFF) + b) = hv;
  }
  asm volatile("s_waitcnt lgkmcnt(0)" ::: "memory");

  f32x4 acc[16];
  short8v a0 = {};

  // ---- T1: X[128x128] @ W1[128x256] -> H1 (chunks 0..7) ----
  #pragma unroll
  for (int fc = 0; fc < 16; ++fc) acc[fc] = (f32x4){0.f, 0.f, 0.f, 0.f};
  #pragma unroll
  for (int c = 0; c < 8; ++c) {
    PIPE(c);
    if ((c & 1) == 0) a0 = read_a(lds, XS_OFF, 256, arow, (c >> 1) * 32 + hi8);
    const unsigned short* bb = wb + (c % 3) * 4096;
    #pragma unroll
    for (int i = 0; i < 8; ++i) {
      short8v b = *(const short8v*)(bb + i * 512 + lane * 8);
      int fc = ((c & 1) << 3) + i;
      acc[fc] = __builtin_amdgcn_mfma_f32_16x16x32_bf16(a0, b, acc[fc], 0, 0, 0);
    }
  }
  epi_gelu<16>(acc, tb1 + e * 256, lds + H1_OFF, 512, lane, wrow0);
  asm volatile("s_waitcnt lgkmcnt(0)" ::: "memory");

  // ---- S1: X @ sW1[128x128] -> SH1 (chunks 8..11) ----
  #pragma unroll
  for (int fc = 0; fc < 8; ++fc) acc[fc] = (f32x4){0.f, 0.f, 0.f, 0.f};
  #pragma unroll
  for (int c8 = 0; c8 < 4; ++c8) {
    int c = 8 + c8;
    PIPE(c);
    a0 = read_a(lds, XS_OFF, 256, arow, c8 * 32 + hi8);
    const unsigned short* bb = wb + (c % 3) * 4096;
    #pragma unroll
    for (int i = 0; i < 8; ++i) {
      short8v b = *(const short8v*)(bb + i * 512 + lane * 8);
      acc[i] = __builtin_amdgcn_mfma_f32_16x16x32_bf16(a0, b, acc[i], 0, 0, 0);
    }
  }
  epi_gelu<8>(acc, sb1 + e * 128, lds + SH1_OFF, 256, lane, wrow0);
  asm volatile("s_waitcnt lgkmcnt(0)" ::: "memory");

  // ---- S2: SH1 @ sW2[128x64] -> score (chunks 12..13) ----
  #pragma unroll
  for (int fc = 0; fc < 4; ++fc) acc[fc] = (f32x4){0.f, 0.f, 0.f, 0.f};
  #pragma unroll
  for (int cc = 0; cc < 2; ++cc) {
    int c = 12 + cc;
    PIPE(c);
    short8v aa0 = read_a(lds, SH1_OFF, 256, arow, (cc * 2) * 32 + hi8);
    short8v aa1 = read_a(lds, SH1_OFF, 256, arow, (cc * 2 + 1) * 32 + hi8);
    const unsigned short* bb = wb + (c % 3) * 4096;
    #pragma unroll
    for (int i = 0; i < 8; ++i) {
      short8v b = *(const short8v*)(bb + i * 512 + lane * 8);
      acc[i & 3] = __builtin_amdgcn_mfma_f32_16x16x32_bf16((i < 4) ? aa0 : aa1, b, acc[i & 3], 0, 0, 0);
    }
  }
  {
    int colb = lane & 15;
    float p[4] = {0.f, 0.f, 0.f, 0.f};
    #pragma unroll
    for (int fc = 0; fc < 4; ++fc) {
      int col = fc * 16 + colb;
      float bv = sb2[e * 64 + col];
      float wv = sW3[e * 64 + col];
      #pragma unroll
      for (int r = 0; r < 4; ++r) p[r] += geluf(acc[fc][r] + bv) * wv;
    }
    #pragma unroll
    for (int r = 0; r < 4; ++r) {
      p[r] += __shfl_xor(p[r], 1);
      p[r] += __shfl_xor(p[r], 2);
      p[r] += __shfl_xor(p[r], 4);
      p[r] += __shfl_xor(p[r], 8);
    }
    if ((lane & 15) == 0) {
      #pragma unroll
      for (int r = 0; r < 4; ++r) {
        int row = wrow0 + ((lane >> 4) << 2) + r;
        if (base + row < count) {
          float v = gwsLds[row] * (p[r] + sb3[e]);
          if (OUTMODE == 0) scoreP[slotbase + row] = v;
          else atomicAdd(&score_out[toksLds[row]], v);
        }
      }
    }
  }

  // ---- T2: H1 @ W2[256x256] -> H2 (chunks 14..29) ----
  #pragma unroll
  for (int fc = 0; fc < 16; ++fc) acc[fc] = (f32x4){0.f, 0.f, 0.f, 0.f};
  #pragma unroll
  for (int t = 0; t < 16; ++t) {
    int c = 14 + t;
    PIPE(c);
    if ((t & 1) == 0) a0 = read_a(lds, H1_OFF, 512, arow, (t >> 1) * 32 + hi8);
    const unsigned short* bb = wb + (c % 3) * 4096;
    #pragma unroll
    for (int i = 0; i < 8; ++i) {
      short8v b = *(const short8v*)(bb + i * 512 + lane * 8);
      int fc = ((t & 1) << 3) + i;
      acc[fc] = __builtin_amdgcn_mfma_f32_16x16x32_bf16(a0, b, acc[fc], 0, 0, 0);
    }
  }
  epi_gelu<16>(acc, tb2 + e * 256, lds + H2_OFF, 512, lane, wrow0);
  asm volatile("s_waitcnt lgkmcnt(0)" ::: "memory");

  // ---- T3: H2 @ W3[256x120pad128] -> out (chunks 30..37) ----
  #pragma unroll
  for (int fc = 0; fc < 8; ++fc) acc[fc] = (f32x4){0.f, 0.f, 0.f, 0.f};
  #pragma unroll
  for (int c8 = 0; c8 < 8; ++c8) {
    int c = 30 + c8;
    PIPE(c);
    a0 = read_a(lds, H2_OFF, 512, arow, c8 * 32 + hi8);
    const unsigned short* bb = wb + (c % 3) * 4096;
    #pragma unroll
    for (int i = 0; i < 8; ++i) {
      short8v b = *(const short8v*)(bb + i * 512 + lane * 8);
      acc[i] = __builtin_amdgcn_mfma_f32_16x16x32_bf16(a0, b, acc[i], 0, 0, 0);
    }
  }
  {
    int colb = lane & 15;
    int rbase = wrow0 + ((lane >> 4) << 2);
    #pragma unroll
    for (int r = 0; r < 4; ++r) {
      int row = rbase + r;
      if (base + row < count) {
        float gw = gwsLds[row];
        if (OUTMODE == 0) {
          unsigned short* dst = trajP + (size_t)(slotbase + row) * 120;
          #pragma unroll
          for (int fc = 0; fc < 8; ++fc) {
            int col = fc * 16 + colb;
            if (col < 120) dst[col] = f2bf(gw * (acc[fc][r] + tb3[e * 120 + col]));
          }
        } else {
          float* dst = traj_out + (size_t)toksLds[row] * 120;
          #pragma unroll
          for (int fc = 0; fc < 8; ++fc) {
            int col = fc * 16 + colb;
            if (col < 120) atomicAdd(&dst[col], gw * (acc[fc][r] + tb3[e * 120 + col]));
          }
        }
      }
    }
  }
}

// ---------------- combine: sum each token's 2 pair partials ----------------
__global__ __launch_bounds__(256) void combine_kernel(
    const int* __restrict__ pairIdx, const int* __restrict__ csum,
    const unsigned short* __restrict__ trajP, const float* __restrict__ scoreP,
    float* __restrict__ traj_out, float* __restrict__ score_out)
{
  int t = blockIdx.x * 256 + threadIdx.x;
  if (t >= N_TOK) return;
  int p0 = pairIdx[2 * t], p1 = pairIdx[2 * t + 1];
  int e0 = p0 / N_TOK, e1 = p1 / N_TOK;
  size_t s0 = (size_t)csum[e0] + (p0 - e0 * N_TOK);
  size_t s1 = (size_t)csum[e1] + (p1 - e1 * N_TOK);
  const unsigned short* r0 = trajP + s0 * 120;
  const unsigned short* r1 = trajP + s1 * 120;
  float* o = traj_out + (size_t)t * 120;
  #pragma unroll 6
  for (int i = 0; i < 30; ++i) {
    u16x4 a = *(const u16x4*)(r0 + i * 4);
    u16x4 b = *(const u16x4*)(r1 + i * 4);
    f32x4 v;
    #pragma unroll
    for (int jj = 0; jj < 4; ++jj) v[jj] = bf2f(a[jj]) + bf2f(b[jj]);
    *(f32x4*)(o + i * 4) = v;
  }
  score_out[t] = scoreP[s0] + scoreP[s1];
}

extern "C" void kernel_launch(void* const* d_in, const int* in_sizes, int n_in,
                              void* d_out, int out_size, void* d_ws, size_t ws_size,
                              hipStream_t stream) {
  (void)in_sizes; (void)n_in; (void)out_size;
  const float* x   = (const float*)d_in[0];
  const float* rW1 = (const float*)d_in[1];
  const float* rb1 = (const float*)d_in[2];
  const float* rW2 = (const float*)d_in[3];
  const float* rb2 = (const float*)d_in[4];
  const float* rW3 = (const float*)d_in[5];
  const float* rb3 = (const float*)d_in[6];
  const float* tW1 = (const float*)d_in[7];
  const float* tb1 = (const float*)d_in[8];
  const float* tW2 = (const float*)d_in[9];
  const float* tb2 = (const float*)d_in[10];
  const float* tW3 = (const float*)d_in[11];
  const float* tb3 = (const float*)d_in[12];
  const float* sW1 = (const float*)d_in[13];
  const float* sb1 = (const float*)d_in[14];
  const float* sW2 = (const float*)d_in[15];
  const float* sb2 = (const float*)d_in[16];
  const float* sW3 = (const float*)d_in[17];
  const float* sb3 = (const float*)d_in[18];
  float* out = (float*)d_out;

  // workspace carve (bytes)
  char* wsb = (char*)d_ws;
  int*   cnt     = (int*)(wsb + 0);
  float* probsum = (float*)(wsb + 32);
  int*   csum    = (int*)(wsb + 64);
  int*   pairTok = (int*)(wsb + 96);
  float* pairW   = (float*)(wsb + 96 + (size_t)6 * N_TOK * 4);
  int*   pairIdx = (int*)(wsb + 96 + (size_t)12 * N_TOK * 4);
  float* scoreP  = (float*)(wsb + 96 + (size_t)14 * N_TOK * 4);
  unsigned short* blob = (unsigned short*)(wsb + 96 + (size_t)16 * N_TOK * 4);
  unsigned short* trajP = (unsigned short*)(wsb + 96 + (size_t)16 * N_TOK * 4 + (size_t)6 * PER_E * 2);
  size_t need = 96 + (size_t)16 * N_TOK * 4 + (size_t)6 * PER_E * 2 + (size_t)2 * N_TOK * 120 * 2;
  bool scratch = ws_size >= need;

  hipMemsetAsync(wsb, 0, 96, stream);
  if (!scratch) hipMemsetAsync(d_out, 0, (size_t)(N_TOK * 121) * 4, stream);

  prep_weights<<<(6 * PER_E) / 256, 256, 0, stream>>>(tW1, tW2, tW3, sW1, sW2, blob);
  router_kernel<<<N_TOK / 32, 256, 0, stream>>>(x, rW1, rb1, rW2, rb2, rW3, rb3,
                                                out + PROB_OFF, pairTok, pairW, pairIdx, cnt, probsum);
  aux_kernel<<<1, 64, 0, stream>>>(probsum, cnt, csum, out + AUX_OFF);
  if (scratch) {
    expert_kernel<0><<<dim3(N_TOK / TILE, 6), 512, 0, stream>>>(
        x, blob, tb1, tb2, tb3, sb1, sb2, sW3, sb3, pairTok, pairW, cnt, csum,
        out + TRAJ_OFF, out + SCORE_OFF, trajP, scoreP);
    combine_kernel<<<N_TOK / 256, 256, 0, stream>>>(pairIdx, csum, trajP, scoreP,
                                                    out + TRAJ_OFF, out + SCORE_OFF);
  } else {
    expert_kernel<1><<<dim3(N_TOK / TILE, 6), 512, 0, stream>>>(
        x, blob, tb1, tb2, tb3, sb1, sb2, sW3, sb3, pairTok, pairW, cnt, csum,
        out + TRAJ_OFF, out + SCORE_OFF, trajP, scoreP);
  }
}